// Round 8
// baseline (456.694 us; speedup 1.0000x reference)
//
#include <hip/hip_runtime.h>
#include <math.h>

#define B_   256
#define N_   129
#define C_   768
#define C4_  192
#define HD_  256
#define NSP_ 38
#define NTOK_ (B_*N_)   // 33024

typedef __attribute__((ext_vector_type(8))) short bf16x8;
typedef __attribute__((ext_vector_type(4))) float f32x4;
typedef __attribute__((ext_vector_type(4))) unsigned short u16x4;

static __device__ __forceinline__ unsigned short f2bf(float x) {
  unsigned u = __float_as_uint(x);
  u += 0x7FFFu + ((u >> 16) & 1u);
  return (unsigned short)(u >> 16);
}
static __device__ __forceinline__ float bf2f(unsigned short h) {
  return __uint_as_float(((unsigned)h) << 16);
}
// 3-way RTN split (weights, one-off): residual ~2^-27 |x|
static __device__ __forceinline__ void split3(float x, unsigned short& h,
                                              unsigned short& m, unsigned short& l) {
  h = f2bf(x);
  float r1 = x - bf2f(h);
  m = f2bf(r1);
  float r2 = r1 - bf2f(m);
  l = f2bf(r2);
}

// ---------- prep: W1 frag split (0..767) | M=W2@V1 (768..959) | dv (960) | clsnorm (961..1216) ----------
__global__ __launch_bounds__(256) void k_prep(const float* __restrict__ W1,
                                              const float* __restrict__ W2,
                                              const float* __restrict__ V1,
                                              const float* __restrict__ b2,
                                              const float* __restrict__ c1,
                                              const float* __restrict__ F,
                                              unsigned short* __restrict__ W1h,
                                              unsigned short* __restrict__ W1m,
                                              unsigned short* __restrict__ W1l,
                                              float* __restrict__ Mm,
                                              float* __restrict__ dv,
                                              float* __restrict__ cls_n,
                                              float* __restrict__ cls_nT) {
  const int bid = blockIdx.x;
  const int t = threadIdx.x;
  if (bid < 768) {                 // W1 fragment split, k=bid, n=t
    if (t < C4_) {
      const int k = bid, n = t;
      const float x = W1[(size_t)k * C4_ + n];
      const int ks = k >> 5, nt = n >> 4;
      const int ll = ((k >> 3) & 3) * 16 + (n & 15);
      const int jj = k & 7;
      const size_t flat = (((size_t)nt * 24 + ks) * 64 + ll) * 8 + jj;
      unsigned short h, m, l;
      split3(x, h, m, l);
      W1h[flat] = h; W1m[flat] = m; W1l[flat] = l;
    }
  } else if (bid < 960) {          // M row i
    const int i = bid - 768, j = t;
    const float* w2r = W2 + (size_t)i * C_;
    float acc = 0.f;
#pragma unroll 8
    for (int k = 0; k < C_; ++k) acc = fmaf(w2r[k], V1[(size_t)k * HD_ + j], acc);
    Mm[(size_t)i * HD_ + j] = acc;
  } else if (bid == 960) {         // dv = b2@V1 + c1
    const int j = t;
    float acc = c1[j];
#pragma unroll 8
    for (int k = 0; k < C_; ++k) acc = fmaf(b2[k], V1[(size_t)k * HD_ + j], acc);
    dv[j] = acc;
  } else {                         // clsnorm for b = bid-961
    const int b = bid - 961;
    const float* row = F + (size_t)b * (N_ * C_);
    float s = 0.f;
    for (int k = t; k < C_; k += 256) { float v = row[k]; s += v * v; }
    for (int off = 32; off > 0; off >>= 1) s += __shfl_down(s, off);
    __shared__ float red[4];
    __shared__ float inv_s;
    if ((t & 63) == 0) red[t >> 6] = s;
    __syncthreads();
    if (t == 0) {
      float tot = red[0] + red[1] + red[2] + red[3];
      inv_s = 1.f / fmaxf(sqrtf(tot), 1e-12f);
    }
    __syncthreads();
    const float inv = inv_s;
    for (int k = t; k < C_; k += 256) {
      float v = row[k] * inv;
      cls_n[(size_t)b * C_ + k] = v;
      cls_nT[(size_t)k * B_ + b] = v;
    }
  }
}

// ---------- sim: mask same-label, top-4, keep ranks 2,3 ----------
__global__ __launch_bounds__(256) void k_sim_top4(const float* __restrict__ cls_nT,
                                                  const int* __restrict__ labels,
                                                  int* __restrict__ swap_idx) {
  const int b = blockIdx.x;
  const int t = threadIdx.x;  // candidate j
  __shared__ float a[C_];
  for (int k = t; k < C_; k += 256) a[k] = cls_nT[(size_t)k * B_ + b];
  __syncthreads();
  const int lb = labels[b];
  float s;
  if (labels[t] == lb) {
    s = -INFINITY;
  } else {
    float acc = 0.f;
#pragma unroll 8
    for (int k = 0; k < C_; ++k) acc = fmaf(a[k], cls_nT[(size_t)k * B_ + t], acc);
    s = acc;
  }
  __shared__ float svals[B_];
  __shared__ float wv[4];
  __shared__ int   wi[4];
  __shared__ int   top4[4];
  svals[t] = s;
  for (int it = 0; it < 4; ++it) {
    __syncthreads();
    float v = svals[t]; int idx = t;
    for (int off = 32; off > 0; off >>= 1) {
      float ov = __shfl_down(v, off);
      int   oi = __shfl_down(idx, off);
      if (ov > v || (ov == v && oi < idx)) { v = ov; idx = oi; }
    }
    if ((t & 63) == 0) { wv[t >> 6] = v; wi[t >> 6] = idx; }
    __syncthreads();
    if (t == 0) {
      float bv = wv[0]; int bi = wi[0];
      for (int w = 1; w < 4; ++w)
        if (wv[w] > bv || (wv[w] == bv && wi[w] < bi)) { bv = wv[w]; bi = wi[w]; }
      top4[it] = bi;
      svals[bi] = -INFINITY;
    }
  }
  __syncthreads();
  if (t == 0) { swap_idx[b * 2 + 0] = top4[2]; swap_idx[b * 2 + 1] = top4[3]; }
}

// ---------- fused: stage1 split-bf16 MFMA term-major, stage2 fp32 via LDS-staged M ----------
// 32-row tiles, 1032 blocks. LDS: A-planes (overlaid by Hs[32][204]) + Ms[16][256]. 42.5 KB.
__global__ __launch_bounds__(256) void k_fused4(const float* __restrict__ F,
                                                const unsigned short* __restrict__ W1h,
                                                const unsigned short* __restrict__ W1m,
                                                const unsigned short* __restrict__ W1l,
                                                const float* __restrict__ b1,
                                                const float* __restrict__ Mm,
                                                const float* __restrict__ dv,
                                                const float* __restrict__ V2,
                                                const float* __restrict__ c2,
                                                float* __restrict__ imp) {
  __shared__ __align__(16) char smem[32 * 204 * 4];   // 26112 B: A-planes then Hs overlay
  __shared__ __align__(16) float Ms[16][256];         // 16384 B
  unsigned short (*Ah)[32][40] = (unsigned short(*)[32][40])(smem);
  unsigned short (*Am)[32][40] = (unsigned short(*)[32][40])(smem + 5120);
  unsigned short (*Al)[32][40] = (unsigned short(*)[32][40])(smem + 10240);
  float (*Hs)[204] = (float(*)[204])(smem);           // overlays A (sync'd)

  const int t = threadIdx.x;
  const int w = t >> 6;
  const int l = t & 63;
  const int l15 = l & 15, l4 = l >> 4;
  const int row0 = blockIdx.x * 32;

  f32x4 acc[2][3];
#pragma unroll
  for (int i = 0; i < 2; ++i)
#pragma unroll
    for (int j = 0; j < 3; ++j) acc[i][j] = (f32x4){0.f, 0.f, 0.f, 0.f};

  // staging map: thread -> (row sr, k-quad sk)
  const int sr = t >> 3;        // 0..31
  const int sk = (t & 7) * 4;   // 0..28
  const float* fptr = F + (size_t)(row0 + sr) * C_ + sk;

  float4 p = *(const float4*)(fptr);

  for (int ks = 0; ks < 24; ++ks) {
    const int buf = ks & 1;
    {  // split (h,m truncated — captured downstream; l RTN) and write to LDS
      float xs[4] = {p.x, p.y, p.z, p.w};
      u16x4 hv, mv, lv;
#pragma unroll
      for (int j = 0; j < 4; ++j) {
        const unsigned u = __float_as_uint(xs[j]);
        const float hf = __uint_as_float(u & 0xFFFF0000u);
        const float r1 = xs[j] - hf;
        const unsigned u1 = __float_as_uint(r1);
        const float mf = __uint_as_float(u1 & 0xFFFF0000u);
        const float r2 = r1 - mf;
        hv[j] = (unsigned short)(u >> 16);
        mv[j] = (unsigned short)(u1 >> 16);
        lv[j] = f2bf(r2);
      }
      *(u16x4*)&Ah[buf][sr][sk] = hv;
      *(u16x4*)&Am[buf][sr][sk] = mv;
      *(u16x4*)&Al[buf][sr][sk] = lv;
    }
    if (ks + 1 < 24) p = *(const float4*)(fptr + (ks + 1) * 32);
    __syncthreads();   // tile ready (dbuf)

    bf16x8 afh[2], afm[2], afl[2];
#pragma unroll
    for (int rt = 0; rt < 2; ++rt) {
      afh[rt] = *(const bf16x8*)&Ah[buf][16 * rt + l15][l4 * 8];
      afm[rt] = *(const bf16x8*)&Am[buf][16 * rt + l15][l4 * 8];
      afl[rt] = *(const bf16x8*)&Al[buf][16 * rt + l15][l4 * 8];
    }
    // preload all 9 B fragments (L2), then 6 term-major passes (6 indep MFMAs each).
    bf16x8 bh[3], bm[3], bl[3];
#pragma unroll
    for (int ntl = 0; ntl < 3; ++ntl) {
      const size_t boff = (((size_t)(3 * w + ntl) * 24 + ks) * 64 + l) * 8;
      bh[ntl] = *(const bf16x8*)(W1h + boff);
      bm[ntl] = *(const bf16x8*)(W1m + boff);
      bl[ntl] = *(const bf16x8*)(W1l + boff);
    }
    // per-acc order: hh, hm, mh, mm, hl, lh (identical to r7's MFMA6 -> bitwise-same)
#pragma unroll
    for (int ntl = 0; ntl < 3; ++ntl)
#pragma unroll
      for (int rt = 0; rt < 2; ++rt)
        acc[rt][ntl] = __builtin_amdgcn_mfma_f32_16x16x32_bf16(afh[rt], bh[ntl], acc[rt][ntl], 0, 0, 0);
#pragma unroll
    for (int ntl = 0; ntl < 3; ++ntl)
#pragma unroll
      for (int rt = 0; rt < 2; ++rt)
        acc[rt][ntl] = __builtin_amdgcn_mfma_f32_16x16x32_bf16(afh[rt], bm[ntl], acc[rt][ntl], 0, 0, 0);
#pragma unroll
    for (int ntl = 0; ntl < 3; ++ntl)
#pragma unroll
      for (int rt = 0; rt < 2; ++rt)
        acc[rt][ntl] = __builtin_amdgcn_mfma_f32_16x16x32_bf16(afm[rt], bh[ntl], acc[rt][ntl], 0, 0, 0);
#pragma unroll
    for (int ntl = 0; ntl < 3; ++ntl)
#pragma unroll
      for (int rt = 0; rt < 2; ++rt)
        acc[rt][ntl] = __builtin_amdgcn_mfma_f32_16x16x32_bf16(afm[rt], bm[ntl], acc[rt][ntl], 0, 0, 0);
#pragma unroll
    for (int ntl = 0; ntl < 3; ++ntl)
#pragma unroll
      for (int rt = 0; rt < 2; ++rt)
        acc[rt][ntl] = __builtin_amdgcn_mfma_f32_16x16x32_bf16(afh[rt], bl[ntl], acc[rt][ntl], 0, 0, 0);
#pragma unroll
    for (int ntl = 0; ntl < 3; ++ntl)
#pragma unroll
      for (int rt = 0; rt < 2; ++rt)
        acc[rt][ntl] = __builtin_amdgcn_mfma_f32_16x16x32_bf16(afl[rt], bh[ntl], acc[rt][ntl], 0, 0, 0);
  }

  // epilogue stage1: H = relu(acc + b1) -> fp32 LDS (overlays dead A planes)
  float b1v[3];
#pragma unroll
  for (int ntl = 0; ntl < 3; ++ntl) b1v[ntl] = b1[16 * (3 * w + ntl) + l15];
  __syncthreads();   // all waves done reading A planes
#pragma unroll
  for (int rt = 0; rt < 2; ++rt)
#pragma unroll
    for (int ntl = 0; ntl < 3; ++ntl) {
      const int col = 16 * (3 * w + ntl) + l15;
#pragma unroll
      for (int r = 0; r < 4; ++r) {
        const int row = 16 * rt + l4 * 4 + r;
        Hs[row][col] = fmaxf(acc[rt][ntl][r] + b1v[ntl], 0.f);
      }
    }
  __syncthreads();

  // stage2: pre = H @ M, exact fp32 (r7 semantics, kk order preserved), M staged via LDS
  const int ct = t & 31;   // 32 col-threads * 8 cols = 256
  const int rt2 = t >> 5;  // 8 row-groups * 4 rows = 32
  float acc2[4][8];
#pragma unroll
  for (int i = 0; i < 4; ++i)
#pragma unroll
    for (int j = 0; j < 8; ++j) acc2[i][j] = 0.f;

  for (int c = 0; c < 12; ++c) {   // 12 chunks x 16 kk
    __syncthreads();               // previous chunk's Ms reads done
#pragma unroll
    for (int i2 = 0; i2 < 4; ++i2) {
      const int f = t + i2 * 256;            // 1024 float4 slots
      const int mrow = f >> 6, mc4 = f & 63;
      *(float4*)&Ms[mrow][mc4 * 4] =
          *(const float4*)(Mm + (size_t)(c * 16 + mrow) * HD_ + mc4 * 4);
    }
    __syncthreads();
#pragma unroll
    for (int q = 0; q < 4; ++q) {
      float4 h4[4];
#pragma unroll
      for (int i = 0; i < 4; ++i)
        h4[i] = *(const float4*)&Hs[rt2 * 4 + i][c * 16 + q * 4];
#pragma unroll
      for (int kk2 = 0; kk2 < 4; ++kk2) {
        const float4 m0 = *(const float4*)&Ms[q * 4 + kk2][ct * 8];
        const float4 m1 = *(const float4*)&Ms[q * 4 + kk2][ct * 8 + 4];
        const float mv[8] = {m0.x, m0.y, m0.z, m0.w, m1.x, m1.y, m1.z, m1.w};
#pragma unroll
        for (int i = 0; i < 4; ++i) {
          const float hvv = ((const float*)&h4[i])[kk2];
#pragma unroll
          for (int j = 0; j < 8; ++j) acc2[i][j] = fmaf(hvv, mv[j], acc2[i][j]);
        }
      }
    }
  }

  float dvv[8], v2v[8];
#pragma unroll
  for (int j = 0; j < 8; ++j) { dvv[j] = dv[ct * 8 + j]; v2v[j] = V2[ct * 8 + j]; }
  const float c2v = c2[0];
#pragma unroll
  for (int i = 0; i < 4; ++i) {
    float s = 0.f;
#pragma unroll
    for (int j = 0; j < 8; ++j) {
      float g = fmaxf(acc2[i][j] + dvv[j], 0.f);
      s = fmaf(g, v2v[j], s);
    }
#pragma unroll
    for (int off = 1; off < 32; off <<= 1) s += __shfl_xor(s, off);
    if (ct == 0) imp[(size_t)(row0 + rt2 * 4 + i)] = s + c2v;
  }
}

// ---------- tail: per-b top-38 (wave 0, barrier-free) then blend (all 16 waves) ----------
__global__ __launch_bounds__(1024) void k_tail(const float* __restrict__ imp,
                                               const int* __restrict__ swap_choice,
                                               const int* __restrict__ swap_idx,
                                               const float* __restrict__ F,
                                               const float* __restrict__ cls_n,
                                               float* __restrict__ out) {
  const int b = blockIdx.x;
  const int t = threadIdx.x;
  __shared__ float vals[N_];
  __shared__ int srcL[N_ - 1];
  __shared__ int top[NSP_];
  if (t < 64) {
    for (int i = t; i < N_; i += 64) vals[i] = imp[(size_t)b * N_ + i];
    for (int i = t; i < N_ - 1; i += 64) srcL[i] = -1;
    // wave-internal: DS ops from one wave are ordered; no barrier needed
    for (int it = 0; it < NSP_; ++it) {
      float v = -INFINITY; int idx = N_;
      for (int i = t; i < N_; i += 64) {
        float x = vals[i];
        if (x > v || (x == v && i < idx)) { v = x; idx = i; }
      }
      for (int off = 32; off > 0; off >>= 1) {
        float ov = __shfl_xor(v, off);
        int   oi = __shfl_xor(idx, off);
        if (ov > v || (ov == v && oi < idx)) { v = ov; idx = oi; }
      }
      if (t == 0) { top[it] = idx; vals[idx] = -INFINITY; }
    }
    if (t == 0) {
      for (int it = 0; it < NSP_; ++it) {
        const int idx = top[it];
        const int adj = idx > 0 ? idx - 1 : 0;
        // rank order, last wins (numpy fancy-assign semantics)
        srcL[adj] = swap_idx[b * 2 + swap_choice[b * NSP_ + it]];
      }
    }
  }
  __syncthreads();
  const int tot = N_ * (C_ / 4);              // 24768 float4 per batch
  const float4* fin = (const float4*)F + (size_t)b * tot;
  const float4* cl4 = (const float4*)cls_n;
  float4* o4 = (float4*)out + (size_t)b * tot;
  for (int f = t; f < tot; f += 1024) {
    const int n = f / (C_ / 4);
    float4 x = fin[f];
    float4 y = x;
    if (n > 0) {
      const int s = srcL[n - 1];
      if (s >= 0) y = cl4[(size_t)s * (C_ / 4) + (f - n * (C_ / 4))];
    }
    float4 o;
    o.x = 0.7f * x.x + 0.3f * y.x;
    o.y = 0.7f * x.y + 0.3f * y.y;
    o.z = 0.7f * x.z + 0.3f * y.z;
    o.w = 0.7f * x.w + 0.3f * y.w;
    o4[f] = o;
  }
}

extern "C" void kernel_launch(void* const* d_in, const int* in_sizes, int n_in,
                              void* d_out, int out_size, void* d_ws, size_t ws_size,
                              hipStream_t stream) {
  const float* F   = (const float*)d_in[0];
  const float* W1  = (const float*)d_in[1];
  const float* b1  = (const float*)d_in[2];
  const float* W2  = (const float*)d_in[3];
  const float* b2  = (const float*)d_in[4];
  const float* V1  = (const float*)d_in[5];
  const float* c1  = (const float*)d_in[6];
  const float* V2  = (const float*)d_in[7];
  const float* c2  = (const float*)d_in[8];
  const int* labels      = (const int*)d_in[9];
  const int* swap_choice = (const int*)d_in[10];
  float* out = (float*)d_out;

  char* ws = (char*)d_ws;
  size_t off = 0;
  auto alloc = [&](size_t bytes) -> void* {
    void* p = ws + off;
    off = (off + bytes + 255) & ~(size_t)255;
    return p;
  };
  float* cls_n   = (float*)alloc((size_t)B_ * C_ * 4);
  float* cls_nT  = (float*)alloc((size_t)C_ * B_ * 4);
  unsigned short* W1h = (unsigned short*)alloc((size_t)C_ * C4_ * 2);
  unsigned short* W1m = (unsigned short*)alloc((size_t)C_ * C4_ * 2);
  unsigned short* W1l = (unsigned short*)alloc((size_t)C_ * C4_ * 2);
  float* Mm      = (float*)alloc((size_t)C4_ * HD_ * 4);
  float* dv      = (float*)alloc((size_t)HD_ * 4);
  float* imp     = (float*)alloc((size_t)NTOK_ * 4);
  int*   swapIdx = (int*)alloc((size_t)B_ * 2 * 4);
  if (off > ws_size) return;

  k_prep<<<1217, 256, 0, stream>>>(W1, W2, V1, b2, c1, F, W1h, W1m, W1l, Mm, dv, cls_n, cls_nT);
  k_sim_top4<<<B_, 256, 0, stream>>>(cls_nT, labels, swapIdx);
  k_fused4<<<NTOK_ / 32, 256, 0, stream>>>(F, W1h, W1m, W1l, b1, Mm, dv, V2, c2, imp);
  k_tail<<<B_, 1024, 0, stream>>>(imp, swap_choice, swapIdx, F, cls_n, out);
}